// Round 8
// baseline (13943.047 us; speedup 1.0000x reference)
//
#include <hip/hip_runtime.h>
#include <math.h>

// ---------------------------------------------------------------------------
// Persistent-RNN LSTM for MI355X.
//   B=128, T=512, IN=64, H=1024, 2 layers, head OUT=1 on last step.
// Design (round 8: LLC-direct h transport, no cache invalidates):
//  - 256 WGs x 512 threads (8 waves), cooperative launch, 1 WG/CU.
//  - WG (gb = wg>>1, bh = wg&1) owns 8 h-cols x 64 batch rows => 32 gate rows
//    (round-7 tiling: halved per-WG h reads, 16B-wide stores).
//  - h transport: stores are write-through sc0 sc1 (no L1/L2 allocate, data
//    lands at LLC); ALL h reads are __builtin_nontemporal_load (nt: no
//    L1/L2 allocate).  Since nothing ever allocates h lines into L1/L2,
//    NT reads always stream from the LLC => always fresh => NO buffer_inv
//    anywhere.  This removes the per-step L2-invalidate + cold-miss storms
//    (round-7: 23 MB/step L2 refills, latency-exposed in the MFMA loop),
//    trading them for ~64 MB/step of overlappable LLC streaming.
//  - Barrier: pure arrive/release, no XCD leaders, no invs:
//      members RMW garr[wg>>5] (8 lines); group leaders add 32 to global,
//      poll global to 256*epoch, set per-group release flag; members poll
//      their group flag.  All counters monotonic.
//  - Weights: layer0 [Uh0|Wx0] 32 rows x 1088 f16 in LDS (70 KB); layer1
//    64 half8 frags/lane (256 regs -> unified VGPR/AGPR file).
//  - mfma_f32_16x16x32_f16; one A-frag load feeds 4 MFMAs (lowhalf).
//  - Cell math fp32, fast __expf/__fdividef sigmoid/tanh (verified numerics);
//    cell gather = single shfl_xor(8) pair.
//  - ROW-MAJOR h layout (round-5's blocked layout regressed badly).
// ---------------------------------------------------------------------------

#define Hd 1024
#define Bd 128
#define Td 512
#define INd 64
#define NWG 256
#define NTHR 512

typedef _Float16 f16;
typedef _Float16 half8 __attribute__((ext_vector_type(8)));
typedef float f32x4 __attribute__((ext_vector_type(4)));

// sync[] layout (uint index):
//   [0]           : global step counter (group leaders add 32; target 256*ep)
//   [32 + 32*g]   : per-group arrival counter (monotonic), g = wg>>5
//   [288 + 32*g]  : per-group release flag (epoch)
// zero first 640 uints.

__device__ __forceinline__ float fsigm(float x) {
    return __fdividef(1.f, 1.f + __expf(-x));
}
__device__ __forceinline__ float ftanh_(float x) {
    return 1.f - __fdividef(2.f, 1.f + __expf(2.f * x));
}

// ---------------- init: bi0/bi1, zero h buffers, zero sync ----------------
__global__ __launch_bounds__(512) void init_state(
    const float* __restrict__ bnd, const float* __restrict__ Wb0,
    const float* __restrict__ bb0, const float* __restrict__ Wb1,
    const float* __restrict__ bb1,
    float* __restrict__ bi0, float* __restrict__ bi1,
    f16* __restrict__ h0buf, f16* __restrict__ h1buf,
    unsigned int* __restrict__ sync)
{
    int idx = blockIdx.x * 512 + threadIdx.x;   // [0, B*H)
    int b = idx >> 10;
    int h = idx & 1023;
    float b0v = bnd[b * 2 + 0], b1v = bnd[b * 2 + 1];
    bi0[idx] = b0v * Wb0[h * 2 + 0] + b1v * Wb0[h * 2 + 1] + bb0[h];
    bi1[idx] = b0v * Wb1[h * 2 + 0] + b1v * Wb1[h * 2 + 1] + bb1[h];
    h0buf[idx] = (f16)0.f;  h0buf[idx + Bd * Hd] = (f16)0.f;
    h1buf[idx] = (f16)0.f;  h1buf[idx + Bd * Hd] = (f16)0.f;
    if (idx < 640) sync[idx] = 0u;
}

// ---------------- transpose x [B,T,IN] f32 -> xT [T,B,IN] f16 ----------------
__global__ __launch_bounds__(512) void xpose(
    const float* __restrict__ x, f16* __restrict__ xT)
{
    int idx = blockIdx.x * 512 + threadIdx.x;   // [0, B*T*IN)
    int b = idx >> 15;           // T*IN = 32768
    int t = (idx >> 6) & 511;
    int i = idx & 63;
    xT[((size_t)t * Bd + b) * INd + i] = (f16)x[idx];
}

// ---------------- persistent LSTM ----------------
__global__ __launch_bounds__(NTHR, 2) void lstm_persist(
    const f16* __restrict__ xT,
    f16* __restrict__ h0buf, f16* __restrict__ h1buf,
    const float* __restrict__ bi0, const float* __restrict__ bi1,
    const float* __restrict__ Wx0, const float* __restrict__ bx0,
    const float* __restrict__ Uh0, const float* __restrict__ bh0,
    const float* __restrict__ Wx1, const float* __restrict__ bx1,
    const float* __restrict__ Uh1, const float* __restrict__ bh1,
    const float* __restrict__ fcW, const float* __restrict__ fcb,
    float* __restrict__ out, unsigned int* __restrict__ sync)
{
    const int tid  = threadIdx.x;
    const int w    = tid >> 6;        // wave 0..7
    const int lane = tid & 63;
    const int n    = lane & 15;       // frag col within tile
    const int q    = lane >> 4;       // 0..3
    const int wg   = blockIdx.x;
    const int gb   = wg >> 1;         // gate-block 0..127 (8 h-cols)
    const int bh   = wg & 1;          // batch half
    const int hc0  = gb * 8;          // h-col base
    const int hcol = hc0 + (n & 7);   // this lane's cell column
    const bool lowhalf = (w < 4);
    const int p    = lowhalf ? w : (w - 4);
    const int bt   = bh * 64 + p * 16;  // batch-tile base row (per wave)
    const size_t S = (size_t)Bd * Hd;

    __shared__ f16 B0[32 * 1096];       // layer0 weights [32 rows][1088+8 pad]
    __shared__ float xchg[2048];        // l1 exchange: 4 waves x 2 tiles x 256

    // ---- static arrival group (no XCD leaders, no invalidates) ----
    const bool glead = ((wg & 31) == 0);
    unsigned int* garr = sync + 32  + 32 * (wg >> 5);
    unsigned int* grel = sync + 288 + 32 * (wg >> 5);

    // ---- fill B0 (f32 -> f16): row nr -> global gate row ----
    // nr in [0,32): tile t = nr>>4, np = nr&15, gate = t*2 + (np>>3), col np&7
    {
        int nr = tid >> 4;              // 0..31
        int t  = nr >> 4, np = nr & 15;
        int gr = (t * 2 + (np >> 3)) * Hd + hc0 + (np & 7);
        for (int k = tid & 15; k < 1088; k += 16) {
            float v = (k < Hd) ? Uh0[(size_t)gr * Hd + k]
                               : Wx0[(size_t)gr * INd + (k - Hd)];
            B0[nr * 1096 + k] = (f16)v;
        }
    }

    // ---- preload layer1 B frags (both tiles) into regs (my k-half) ----
    half8 b1f0[32], b1f1[32];
    {
        const float* Wsrc = lowhalf ? Wx1 : Uh1;
        int gr0 = (0 + (n >> 3)) * Hd + hcol;    // tile0: i / f row
        int gr1 = (2 + (n >> 3)) * Hd + hcol;    // tile1: o / g row
        const float* rp0 = Wsrc + (size_t)gr0 * Hd + q * 8;
        const float* rp1 = Wsrc + (size_t)gr1 * Hd + q * 8;
        #pragma unroll
        for (int kk = 0; kk < 32; ++kk) {
            half8 h0v, h1v;
            #pragma unroll
            for (int j = 0; j < 8; ++j) {
                h0v[j] = (f16)rp0[kk * 32 + j];
                h1v[j] = (f16)rp1[kk * 32 + j];
            }
            b1f0[kk] = h0v;
            b1f1[kk] = h1v;
        }
    }

    // ---- per-lane biases & c-state ----
    float gb0[4], gb1[4], bia0[4], bia1[4];
    #pragma unroll
    for (int g = 0; g < 4; ++g) {
        gb0[g] = bx0[g * Hd + hcol] + bh0[g * Hd + hcol];
        gb1[g] = bx1[g * Hd + hcol] + bh1[g * Hd + hcol];
    }
    #pragma unroll
    for (int r = 0; r < 4; ++r) {
        int row = bt + q * 4 + r;
        bia0[r] = bi0[(size_t)row * Hd + hcol];
        bia1[r] = bi1[(size_t)row * Hd + hcol];
    }
    f32x4 c0v = {0.f, 0.f, 0.f, 0.f};
    f32x4 c1v = {0.f, 0.f, 0.f, 0.f};

    __syncthreads();   // B0 ready

    unsigned epoch = 0;

    for (int s = -1; s <= 511; ++s) {
        const bool do_l0 = (s < 511);
        const bool do_l1 = (s >= 0);
        const int pr = s & 1;                 // s=-1 -> 1
        const f16* h0r = h0buf + (size_t)pr * S;
        f16*       h0w = h0buf + (size_t)(1 - pr) * S;
        const f16* h1r = h1buf + (size_t)(1 - pr) * S;
        f16*       h1w = h1buf + (size_t)pr * S;

        f32x4 a0a = {0.f,0.f,0.f,0.f}, a0b = {0.f,0.f,0.f,0.f};
        f32x4 a1a = {0.f,0.f,0.f,0.f}, a1b = {0.f,0.f,0.f,0.f};

        if (lowhalf) {
            const half8* pA  = (const half8*)(h0r + (size_t)(bt + n) * Hd + q*8);
            const half8* pB0t = (const half8*)(&B0[n        * 1096 + q * 8]);
            const half8* pB1t = (const half8*)(&B0[(16 + n) * 1096 + q * 8]);
            if (do_l0 && do_l1) {
                #pragma unroll
                for (int kk = 0; kk < 32; ++kk) {
                    half8 A = __builtin_nontemporal_load(&pA[kk*4]);
                    a0a = __builtin_amdgcn_mfma_f32_16x16x32_f16(A, pB0t[kk*4], a0a, 0,0,0);
                    a0b = __builtin_amdgcn_mfma_f32_16x16x32_f16(A, pB1t[kk*4], a0b, 0,0,0);
                    a1a = __builtin_amdgcn_mfma_f32_16x16x32_f16(A, b1f0[kk], a1a, 0,0,0);
                    a1b = __builtin_amdgcn_mfma_f32_16x16x32_f16(A, b1f1[kk], a1b, 0,0,0);
                }
            } else if (do_l0) {          // s == -1
                #pragma unroll
                for (int kk = 0; kk < 32; ++kk) {
                    half8 A = __builtin_nontemporal_load(&pA[kk*4]);
                    a0a = __builtin_amdgcn_mfma_f32_16x16x32_f16(A, pB0t[kk*4], a0a, 0,0,0);
                    a0b = __builtin_amdgcn_mfma_f32_16x16x32_f16(A, pB1t[kk*4], a0b, 0,0,0);
                }
            } else {                     // s == 511: l1-khalf0 only
                #pragma unroll
                for (int kk = 0; kk < 32; ++kk) {
                    half8 A = __builtin_nontemporal_load(&pA[kk*4]);
                    a1a = __builtin_amdgcn_mfma_f32_16x16x32_f16(A, b1f0[kk], a1a, 0,0,0);
                    a1b = __builtin_amdgcn_mfma_f32_16x16x32_f16(A, b1f1[kk], a1b, 0,0,0);
                }
            }
            if (do_l0) {                 // x-projection chunks (k = 1024..1087)
                const f16* xt = xT + (size_t)(s + 1) * Bd * INd;
                const half8* pX = (const half8*)(xt + (size_t)(bt + n) * INd + q*8);
                #pragma unroll
                for (int kk = 0; kk < 2; ++kk) {
                    half8 X = pX[kk*4];
                    a0a = __builtin_amdgcn_mfma_f32_16x16x32_f16(X, pB0t[(32+kk)*4], a0a, 0,0,0);
                    a0b = __builtin_amdgcn_mfma_f32_16x16x32_f16(X, pB1t[(32+kk)*4], a0b, 0,0,0);
                }
            }
        } else if (do_l1) {              // waves 4-7: layer1 k-half 1 (A = h1)
            const half8* pH = (const half8*)(h1r + (size_t)(bt + n) * Hd + q*8);
            #pragma unroll
            for (int kk = 0; kk < 32; ++kk) {
                half8 A = __builtin_nontemporal_load(&pH[kk*4]);
                a1a = __builtin_amdgcn_mfma_f32_16x16x32_f16(A, b1f0[kk], a1a, 0,0,0);
                a1b = __builtin_amdgcn_mfma_f32_16x16x32_f16(A, b1f1[kk], a1b, 0,0,0);
            }
        }

        // ---- exchange l1 khalf0 partials: lowhalf wave p -> highhalf wave p ----
        if (lowhalf && do_l1) {
            *(f32x4*)&xchg[p * 512 +       lane * 4] = a1a;
            *(f32x4*)&xchg[p * 512 + 256 + lane * 4] = a1b;
        }
        __syncthreads();
        f32x4 g1a, g1b;
        if (!lowhalf && do_l1) {
            g1a = a1a + *(const f32x4*)&xchg[p * 512 +       lane * 4];
            g1b = a1b + *(const f32x4*)&xchg[p * 512 + 256 + lane * 4];
        }

        // ---- cell update (fp32, fast sigmoid/tanh), write h (f16 WT) ----
        // accA = tile0 (i|f), accB = tile1 (o|g).  Lane n<8: own=i,o;
        // xor8 partner holds f,g for the same column.  Lanes n>=8 compute
        // redundantly and don't store.  Store = 8 contiguous cols x 2B.
        auto cell = [&](f32x4 accA, f32x4 accB, const float* gbx,
                        const float* bia, f32x4& cst, f16* hw) {
            #pragma unroll
            for (int r = 0; r < 4; ++r) {
                float t0  = accA[r];
                float t1  = accB[r];
                float t0x = __shfl_xor(t0, 8);
                float t1x = __shfl_xor(t1, 8);
                float I = fsigm(t0  + gbx[0]);
                float F = fsigm(t0x + gbx[1] + bia[r]);
                float O = fsigm(t1  + gbx[2]);
                float G = ftanh_(t1x + gbx[3]);
                float c = F * cst[r] + I * G;
                cst[r] = c;
                float h = O * ftanh_(c);
                if (n < 8) {
                    union { f16 hf; unsigned short us; } cv; cv.hf = (f16)h;
                    // write-through to LLC (sc0 sc1): no L1/L2 allocate, so
                    // NT readers always see fresh LLC data — no invs needed.
                    __hip_atomic_store(
                        (unsigned short*)&hw[(size_t)(bt + q * 4 + r) * Hd + hc0 + n],
                        cv.us, __ATOMIC_RELAXED, __HIP_MEMORY_SCOPE_AGENT);
                }
            }
        };
        if (lowhalf) { if (do_l0) cell(a0a, a0b, gb0, bia0, c0v, h0w); }
        else         { if (do_l1) cell(g1a, g1b, gb1, bia1, c1v, h1w); }

        // ---- pure arrive/release grid barrier (no cache maintenance) ----
        // __syncthreads drains every wave's WT stores (vmcnt 0) before tid0
        // signals arrival, so all h-state is at the LLC coherence point.
        __syncthreads();
        if (tid == 0) {
            const unsigned tgt = epoch + 1u;
            __hip_atomic_fetch_add(garr, 1u, __ATOMIC_RELAXED,
                                   __HIP_MEMORY_SCOPE_AGENT);
            if (glead) {
                while (__hip_atomic_load(garr, __ATOMIC_RELAXED,
                                         __HIP_MEMORY_SCOPE_AGENT) < 32u * tgt)
                    __builtin_amdgcn_s_sleep(1);
                __hip_atomic_fetch_add(sync, 32u, __ATOMIC_RELAXED,
                                       __HIP_MEMORY_SCOPE_AGENT);
                while (__hip_atomic_load(sync, __ATOMIC_RELAXED,
                                         __HIP_MEMORY_SCOPE_AGENT) < NWG * tgt)
                    __builtin_amdgcn_s_sleep(1);
                __hip_atomic_store(grel, tgt, __ATOMIC_RELAXED,
                                   __HIP_MEMORY_SCOPE_AGENT);
            } else {
                while (__hip_atomic_load(grel, __ATOMIC_RELAXED,
                                         __HIP_MEMORY_SCOPE_AGENT) < tgt)
                    __builtin_amdgcn_s_sleep(1);
            }
        }
        epoch++;
        __syncthreads();
    }

    // ---- fc head: out[b] = fcW . h1(511)[b] + fcb ----
    // Normal loads are safe: h lines were never allocated into L1/L2, so the
    // first cached read misses and pulls fresh data from the LLC.
    if (blockIdx.x < Bd) {
        int b = blockIdx.x;
        const f16* hf = h1buf + S + (size_t)b * Hd;   // parity 1 holds h1(511)
        int k = tid * 2;
        float sum = (float)hf[k] * fcW[k] + (float)hf[k + 1] * fcW[k + 1];
        #pragma unroll
        for (int off = 32; off > 0; off >>= 1) sum += __shfl_down(sum, off);
        float* red = xchg;
        if (lane == 0) red[w] = sum;
        __syncthreads();
        if (tid == 0) {
            float t = 0.f;
            #pragma unroll
            for (int i = 0; i < 8; ++i) t += red[i];
            out[b] = t + fcb[0];
        }
    }
}

// ---------------------------------------------------------------------------
extern "C" void kernel_launch(void* const* d_in, const int* in_sizes, int n_in,
                              void* d_out, int out_size, void* d_ws, size_t ws_size,
                              hipStream_t stream) {
    const float* x        = (const float*)d_in[0];
    const float* boundary = (const float*)d_in[1];
    const float* Wx0      = (const float*)d_in[2];
    const float* bx0      = (const float*)d_in[3];
    const float* Uh0      = (const float*)d_in[4];
    const float* bh0      = (const float*)d_in[5];
    const float* Wb0      = (const float*)d_in[6];
    const float* bb0      = (const float*)d_in[7];
    const float* Wx1      = (const float*)d_in[8];
    const float* bx1      = (const float*)d_in[9];
    const float* Uh1      = (const float*)d_in[10];
    const float* bh1      = (const float*)d_in[11];
    const float* Wb1      = (const float*)d_in[12];
    const float* bb1      = (const float*)d_in[13];
    const float* fcW      = (const float*)d_in[14];
    const float* fcb      = (const float*)d_in[15];
    float* out = (float*)d_out;

    // workspace layout (bytes)
    char* ws = (char*)d_ws;
    f16*   xT    = (f16*)(ws);                       // 8,388,608 B
    f16*   h0buf = (f16*)(ws + 8388608);             //   524,288 B (2 parities)
    f16*   h1buf = (f16*)(ws + 8912896);             //   524,288 B
    float* bi0   = (float*)(ws + 9437184);           //   524,288 B
    float* bi1   = (float*)(ws + 9961472);           //   524,288 B
    unsigned int* sync = (unsigned int*)(ws + 10485760);  // 2,560 B sync block

    init_state<<<256, 512, 0, stream>>>(boundary, Wb0, bb0, Wb1, bb1,
                                        bi0, bi1, h0buf, h1buf, sync);
    xpose<<<8192, 512, 0, stream>>>(x, xT);

    void* args[] = {
        (void*)&xT, (void*)&h0buf, (void*)&h1buf, (void*)&bi0, (void*)&bi1,
        (void*)&Wx0, (void*)&bx0, (void*)&Uh0, (void*)&bh0,
        (void*)&Wx1, (void*)&bx1, (void*)&Uh1, (void*)&bh1,
        (void*)&fcW, (void*)&fcb, (void*)&out, (void*)&sync
    };
    hipLaunchCooperativeKernel((void*)lstm_persist, dim3(NWG), dim3(NTHR),
                               args, 0, stream);
}

// Round 9
// 10422.553 us; speedup vs baseline: 1.3378x; 1.3378x over previous
//
#include <hip/hip_runtime.h>
#include <math.h>

// ---------------------------------------------------------------------------
// Persistent-RNN LSTM for MI355X.
//   B=128, T=512, IN=64, H=1024, 2 layers, head OUT=1 on last step.
// Design (round 9: 2x TLP — 16 waves/CU):
//  - 256 WGs x 1024 threads (16 waves), cooperative launch, 1 WG/CU.
//    Round-8 lesson: bottleneck is load-use LATENCY (NT/LLC-direct loads
//    regressed +6.3us/step at equal FETCH).  8 waves/CU couldn't hide it;
//    this round doubles resident waves per CU.
//  - WG owns 4 h-cols (c0wg = wg*4) x full batch 128 => 16 gate rows.
//    Waves 0-7 (lowhalf): batch tile p=w (16 rows); A = h0(s) rows,
//      compute l0(s+1) (B=Uh0|Wx0) AND l1(s) k-half0 (B=Wx1) — shared loads.
//    Waves 8-15 (highhalf): A = h1(s-1) rows, l1(s) k-half1 (B=Uh1).
//    Exchange: wave 8+p adds lowhalf p's l1k0 partial via LDS, does l1 cell.
//  - ALL weights in LDS (48 rows x 1096 f16 = 105 KB): rows 0-15 l0
//    [Uh0|Wx0], 16-31 Wx1, 32-47 Uh1.  Register-light per wave =>
//    __launch_bounds__(1024,4) forces <=128 VGPR so 16 waves co-reside.
//  - ROW-MAJOR h transport, WT stores sc0 sc1 (round-4/6/7 verified; round-5
//    blocked layout and round-8 NT loads both regressed — do not reintroduce).
//  - Cell math fp32, fast __expf/__fdividef sigmoid/tanh (verified numerics);
//    gate gather shfl_xor(4,8,12) (round-6 pattern); c-state in registers.
//  - Fence-light grid barrier: BYTE-IDENTICAL protocol to round-4/6/7
//    verified kernels (static arrival tree garr[wg>>5]; group leaders
//    aggregate 32 into global; XCD leaders poll global, buffer_inv sc1 AFTER
//    poll, release per-XCD flag; followers poll flag then L1 buffer_inv).
// ---------------------------------------------------------------------------

#define Hd 1024
#define Bd 128
#define Td 512
#define INd 64
#define NWG 256
#define NTHR 1024

typedef _Float16 f16;
typedef _Float16 half8 __attribute__((ext_vector_type(8)));
typedef float f32x4 __attribute__((ext_vector_type(4)));

// sync[] layout (uint index):
//   [0]           : global step counter (group leaders add 32; target 256*ep)
//   [32 + 32*g]   : per-group arrival counter (monotonic), g = wg>>5
//   [288 + 32*x]  : per-XCD release flag (epoch), x = physical XCD
//   [608 + x]     : per-XCD leader-election counter
// zero first 640 uints.

__device__ __forceinline__ float fsigm(float x) {
    return __fdividef(1.f, 1.f + __expf(-x));
}
__device__ __forceinline__ float ftanh_(float x) {
    return 1.f - __fdividef(2.f, 1.f + __expf(2.f * x));
}

// ---------------- init: bi0/bi1, zero h buffers, zero sync ----------------
__global__ __launch_bounds__(512) void init_state(
    const float* __restrict__ bnd, const float* __restrict__ Wb0,
    const float* __restrict__ bb0, const float* __restrict__ Wb1,
    const float* __restrict__ bb1,
    float* __restrict__ bi0, float* __restrict__ bi1,
    f16* __restrict__ h0buf, f16* __restrict__ h1buf,
    unsigned int* __restrict__ sync)
{
    int idx = blockIdx.x * 512 + threadIdx.x;   // [0, B*H)
    int b = idx >> 10;
    int h = idx & 1023;
    float b0v = bnd[b * 2 + 0], b1v = bnd[b * 2 + 1];
    bi0[idx] = b0v * Wb0[h * 2 + 0] + b1v * Wb0[h * 2 + 1] + bb0[h];
    bi1[idx] = b0v * Wb1[h * 2 + 0] + b1v * Wb1[h * 2 + 1] + bb1[h];
    h0buf[idx] = (f16)0.f;  h0buf[idx + Bd * Hd] = (f16)0.f;
    h1buf[idx] = (f16)0.f;  h1buf[idx + Bd * Hd] = (f16)0.f;
    if (idx < 640) sync[idx] = 0u;
}

// ---------------- transpose x [B,T,IN] f32 -> xT [T,B,IN] f16 ----------------
__global__ __launch_bounds__(512) void xpose(
    const float* __restrict__ x, f16* __restrict__ xT)
{
    int idx = blockIdx.x * 512 + threadIdx.x;   // [0, B*T*IN)
    int b = idx >> 15;           // T*IN = 32768
    int t = (idx >> 6) & 511;
    int i = idx & 63;
    xT[((size_t)t * Bd + b) * INd + i] = (f16)x[idx];
}

// ---------------- persistent LSTM ----------------
__global__ __launch_bounds__(NTHR, 4) void lstm_persist(
    const f16* __restrict__ xT,
    f16* __restrict__ h0buf, f16* __restrict__ h1buf,
    const float* __restrict__ bi0, const float* __restrict__ bi1,
    const float* __restrict__ Wx0, const float* __restrict__ bx0,
    const float* __restrict__ Uh0, const float* __restrict__ bh0,
    const float* __restrict__ Wx1, const float* __restrict__ bx1,
    const float* __restrict__ Uh1, const float* __restrict__ bh1,
    const float* __restrict__ fcW, const float* __restrict__ fcb,
    float* __restrict__ out, unsigned int* __restrict__ sync)
{
    const int tid  = threadIdx.x;
    const int w    = tid >> 6;        // wave 0..15
    const int lane = tid & 63;
    const int n    = lane & 15;       // frag col (gate-col within WG)
    const int q    = lane >> 4;       // 0..3
    const int wg   = blockIdx.x;
    const int c0wg = wg * 4;          // h-column base of this WG
    const int hcol = c0wg + (n & 3);
    const int gid  = n >> 2;          // gate group of my frag col
    const bool lowhalf = (w < 8);
    const int p    = lowhalf ? w : (w - 8);   // batch tile 0..7 (16 rows)
    const size_t S = (size_t)Bd * Hd;

    // weights: rows 0-15 l0 [Uh0|Wx0] (K=1088); 16-31 Wx1; 32-47 Uh1 (K=1024)
    __shared__ f16 WL[48 * 1096];       // 105,216 B
    __shared__ float xchg[2048];        // 8 slots x 256 floats (8 KB)

    // ---- static arrival group + physical-XCD leader election ----
    const bool glead = ((wg & 31) == 0);
    unsigned int* garr = sync + 32 + 32 * (wg >> 5);
    int  xcd  = 0;
    bool lead = false;
    unsigned int* relp = nullptr;
    if (tid == 0) {
        asm volatile("s_getreg_b32 %0, hwreg(HW_REG_XCC_ID)" : "=s"(xcd));
        xcd &= 7;
        unsigned r = __hip_atomic_fetch_add(&sync[608 + xcd], 1u,
                         __ATOMIC_RELAXED, __HIP_MEMORY_SCOPE_AGENT);
        lead = (r == 0u);
        relp = sync + 288 + 32 * xcd;
    }

    // ---- fill WL (f32 -> f16) ----
    {
        int nr = tid >> 4;              // 0..63
        if (nr < 48) {
            int loc = nr & 15;
            int gr = (loc >> 2) * Hd + c0wg + (loc & 3);
            if (nr < 16) {
                for (int k = tid & 15; k < 1088; k += 16) {
                    float v = (k < Hd) ? Uh0[(size_t)gr * Hd + k]
                                       : Wx0[(size_t)gr * INd + (k - Hd)];
                    WL[nr * 1096 + k] = (f16)v;
                }
            } else {
                const float* Wsrc = (nr < 32) ? Wx1 : Uh1;
                for (int k = tid & 15; k < 1024; k += 16)
                    WL[nr * 1096 + k] = (f16)Wsrc[(size_t)gr * Hd + k];
            }
        }
    }

    // ---- per-lane biases & c-state (role-specific) ----
    float gbx[4], bia[4];
    {
        const float* bxp = lowhalf ? bx0 : bx1;
        const float* bhp = lowhalf ? bh0 : bh1;
        const float* bip = lowhalf ? bi0 : bi1;
        #pragma unroll
        for (int g = 0; g < 4; ++g)
            gbx[g] = bxp[g * Hd + hcol] + bhp[g * Hd + hcol];
        #pragma unroll
        for (int r = 0; r < 4; ++r)
            bia[r] = bip[(size_t)(p * 16 + q * 4 + r) * Hd + hcol];
    }
    f32x4 cst = {0.f, 0.f, 0.f, 0.f};

    __syncthreads();   // WL ready

    unsigned epoch = 0;

    for (int s = -1; s <= 511; ++s) {
        const bool do_l0 = (s < 511);
        const bool do_l1 = (s >= 0);
        const int pr = s & 1;                 // s=-1 -> 1
        const f16* h0r = h0buf + (size_t)pr * S;
        f16*       h0w = h0buf + (size_t)(1 - pr) * S;
        const f16* h1r = h1buf + (size_t)(1 - pr) * S;
        f16*       h1w = h1buf + (size_t)pr * S;

        f32x4 a0 = {0.f,0.f,0.f,0.f};
        f32x4 a1 = {0.f,0.f,0.f,0.f};

        if (lowhalf) {
            const half8* pA  = (const half8*)(h0r + (size_t)(p*16 + n) * Hd + q*8);
            const half8* pB0 = (const half8*)(&WL[n         * 1096 + q * 8]);
            const half8* pB1 = (const half8*)(&WL[(16 + n)  * 1096 + q * 8]);
            if (do_l0 && do_l1) {
                #pragma unroll 8
                for (int kk = 0; kk < 32; ++kk) {
                    half8 A = pA[kk*4];
                    a0 = __builtin_amdgcn_mfma_f32_16x16x32_f16(A, pB0[kk*4], a0, 0,0,0);
                    a1 = __builtin_amdgcn_mfma_f32_16x16x32_f16(A, pB1[kk*4], a1, 0,0,0);
                }
            } else if (do_l0) {          // s == -1
                #pragma unroll 8
                for (int kk = 0; kk < 32; ++kk) {
                    half8 A = pA[kk*4];
                    a0 = __builtin_amdgcn_mfma_f32_16x16x32_f16(A, pB0[kk*4], a0, 0,0,0);
                }
            } else {                     // s == 511: l1 k-half0 only
                #pragma unroll 8
                for (int kk = 0; kk < 32; ++kk) {
                    half8 A = pA[kk*4];
                    a1 = __builtin_amdgcn_mfma_f32_16x16x32_f16(A, pB1[kk*4], a1, 0,0,0);
                }
            }
            if (do_l0) {                 // x-projection chunks (k = 1024..1087)
                const f16* xt = xT + (size_t)(s + 1) * Bd * INd;
                const half8* pX = (const half8*)(xt + (size_t)(p*16 + n) * INd + q*8);
                #pragma unroll
                for (int kk = 0; kk < 2; ++kk)
                    a0 = __builtin_amdgcn_mfma_f32_16x16x32_f16(
                             pX[kk*4], pB0[(32 + kk) * 4], a0, 0,0,0);
            }
        } else if (do_l1) {              // waves 8-15: l1 k-half1 (A = h1)
            const half8* pA  = (const half8*)(h1r + (size_t)(p*16 + n) * Hd + q*8);
            const half8* pB1 = (const half8*)(&WL[(32 + n) * 1096 + q * 8]);
            #pragma unroll 8
            for (int kk = 0; kk < 32; ++kk) {
                half8 A = pA[kk*4];
                a1 = __builtin_amdgcn_mfma_f32_16x16x32_f16(A, pB1[kk*4], a1, 0,0,0);
            }
        }

        // ---- exchange l1 khalf0 partials: lowhalf wave p -> highhalf wave 8+p ----
        if (lowhalf && do_l1)
            *(f32x4*)&xchg[p * 256 + lane * 4] = a1;
        __syncthreads();
        f32x4 g1;
        if (!lowhalf && do_l1)
            g1 = a1 + *(const f32x4*)&xchg[p * 256 + lane * 4];

        // ---- cell update (fp32, fast sigmoid/tanh), write h (f16 WT) ----
        auto cell = [&](f32x4 acc, f16* hw) {
            #pragma unroll
            for (int r = 0; r < 4; ++r) {
                float own = acc[r];
                float v4  = __shfl_xor(own, 4);
                float v8  = __shfl_xor(own, 8);
                float v12 = __shfl_xor(own, 12);
                float ip = gid==0?own: gid==1?v4 : gid==2?v8 : v12;
                float fp = gid==0?v4 : gid==1?own: gid==2?v12: v8;
                float op = gid==0?v8 : gid==1?v12: gid==2?own: v4;
                float gp = gid==0?v12: gid==1?v8 : gid==2?v4 : own;
                float I = fsigm(ip + gbx[0]);
                float F = fsigm(fp + gbx[1] + bia[r]);
                float O = fsigm(op + gbx[2]);
                float G = ftanh_(gp + gbx[3]);
                float c = F * cst[r] + I * G;
                cst[r] = c;
                float h = O * ftanh_(c);
                if (n < 4) {
                    union { f16 hf; unsigned short us; } cv; cv.hf = (f16)h;
                    // write-through to LLC (sc0 sc1): never dirties L2.
                    __hip_atomic_store(
                        (unsigned short*)&hw[(size_t)(p * 16 + q * 4 + r) * Hd + c0wg + n],
                        cv.us, __ATOMIC_RELAXED, __HIP_MEMORY_SCOPE_AGENT);
                }
            }
        };
        if (lowhalf) { if (do_l0) cell(a0, h0w); }
        else         { if (do_l1) cell(g1, h1w); }

        // ---- fence-light grid barrier (identical to round-4/6/7) ----
        // __syncthreads drains every wave's WT stores (vmcnt 0) before tid0
        // signals arrival, so all h-state is at the LLC coherence point.
        __syncthreads();
        if (tid == 0) {
            const unsigned tgt = epoch + 1u;
            __hip_atomic_fetch_add(garr, 1u, __ATOMIC_RELAXED,
                                   __HIP_MEMORY_SCOPE_AGENT);
            if (glead) {
                while (__hip_atomic_load(garr, __ATOMIC_RELAXED,
                                         __HIP_MEMORY_SCOPE_AGENT) < 32u * tgt)
                    __builtin_amdgcn_s_sleep(1);
                __hip_atomic_fetch_add(sync, 32u, __ATOMIC_RELAXED,
                                       __HIP_MEMORY_SCOPE_AGENT);
            }
            if (lead) {
                while (__hip_atomic_load(sync, __ATOMIC_RELAXED,
                                         __HIP_MEMORY_SCOPE_AGENT) < NWG * tgt)
                    __builtin_amdgcn_s_sleep(1);
                // one L2(+L1) invalidate for the whole XCD, completed before
                // the release flag is published.
                asm volatile("buffer_inv sc1\n\ts_waitcnt vmcnt(0)" ::: "memory");
                __hip_atomic_store(relp, tgt, __ATOMIC_RELAXED,
                                   __HIP_MEMORY_SCOPE_AGENT);
            } else {
                while (__hip_atomic_load(relp, __ATOMIC_RELAXED,
                                         __HIP_MEMORY_SCOPE_AGENT) < tgt)
                    __builtin_amdgcn_s_sleep(1);
                // per-CU L1 invalidate only; leader already cleaned our L2.
                asm volatile("buffer_inv\n\ts_waitcnt vmcnt(0)" ::: "memory");
            }
        }
        epoch++;
        __syncthreads();
    }

    // ---- fc head: out[b] = fcW . h1(511)[b] + fcb ----
    if (blockIdx.x < Bd) {
        int b = blockIdx.x;
        if (tid < 512) {
            const f16* hf = h1buf + S + (size_t)b * Hd;   // parity 1 = h1(511)
            int k = tid * 2;
            float sum = (float)hf[k] * fcW[k] + (float)hf[k + 1] * fcW[k + 1];
            #pragma unroll
            for (int off = 32; off > 0; off >>= 1) sum += __shfl_down(sum, off);
            if (lane == 0) xchg[w] = sum;
        }
        __syncthreads();
        if (tid == 0) {
            float t = 0.f;
            #pragma unroll
            for (int i = 0; i < 8; ++i) t += xchg[i];
            out[b] = t + fcb[0];
        }
    }
}

// ---------------------------------------------------------------------------
extern "C" void kernel_launch(void* const* d_in, const int* in_sizes, int n_in,
                              void* d_out, int out_size, void* d_ws, size_t ws_size,
                              hipStream_t stream) {
    const float* x        = (const float*)d_in[0];
    const float* boundary = (const float*)d_in[1];
    const float* Wx0      = (const float*)d_in[2];
    const float* bx0      = (const float*)d_in[3];
    const float* Uh0      = (const float*)d_in[4];
    const float* bh0      = (const float*)d_in[5];
    const float* Wb0      = (const float*)d_in[6];
    const float* bb0      = (const float*)d_in[7];
    const float* Wx1      = (const float*)d_in[8];
    const float* bx1      = (const float*)d_in[9];
    const float* Uh1      = (const float*)d_in[10];
    const float* bh1      = (const float*)d_in[11];
    const float* Wb1      = (const float*)d_in[12];
    const float* bb1      = (const float*)d_in[13];
    const float* fcW      = (const float*)d_in[14];
    const float* fcb      = (const float*)d_in[15];
    float* out = (float*)d_out;

    // workspace layout (bytes)
    char* ws = (char*)d_ws;
    f16*   xT    = (f16*)(ws);                       // 8,388,608 B
    f16*   h0buf = (f16*)(ws + 8388608);             //   524,288 B (2 parities)
    f16*   h1buf = (f16*)(ws + 8912896);             //   524,288 B
    float* bi0   = (float*)(ws + 9437184);           //   524,288 B
    float* bi1   = (float*)(ws + 9961472);           //   524,288 B
    unsigned int* sync = (unsigned int*)(ws + 10485760);  // 2,560 B sync block

    init_state<<<256, 512, 0, stream>>>(boundary, Wb0, bb0, Wb1, bb1,
                                        bi0, bi1, h0buf, h1buf, sync);
    xpose<<<8192, 512, 0, stream>>>(x, xT);

    void* args[] = {
        (void*)&xT, (void*)&h0buf, (void*)&h1buf, (void*)&bi0, (void*)&bi1,
        (void*)&Wx0, (void*)&bx0, (void*)&Uh0, (void*)&bh0,
        (void*)&Wx1, (void*)&bx1, (void*)&Uh1, (void*)&bh1,
        (void*)&fcW, (void*)&fcb, (void*)&out, (void*)&sync
    };
    hipLaunchCooperativeKernel((void*)lstm_persist, dim3(NWG), dim3(NTHR),
                               args, 0, stream);
}